// Round 14
// baseline (319.002 us; speedup 1.0000x reference)
//
#include <hip/hip_runtime.h>
#include <math.h>

typedef unsigned int   uint;
typedef unsigned short ushort;

#define N_NODES 50000
#define DIM     128
#define N_EDGES 800000
#define N_UID   4096
#define LN_EPS  1e-5f
#define RST     132   // padded LDS row stride for fp32 y
#define XST     136   // padded LDS row stride for bf16 x
#define NBUCK   196   // ceil(50000/256) buckets of 256 nodes
#define PCHUNK  4096  // edges per part block

typedef __attribute__((ext_vector_type(8))) short bf16x8;
typedef __attribute__((ext_vector_type(4))) float f32x4;
typedef __attribute__((ext_vector_type(4))) uint  u32x4;

// ---- bf16 helpers (storage only; math fp32) ----
__device__ __forceinline__ float bf_lo(uint u) { return __builtin_bit_cast(float, u << 16); }
__device__ __forceinline__ float bf_hi(uint u) { return __builtin_bit_cast(float, u & 0xffff0000u); }
__device__ __forceinline__ uint pack_bf16(float a, float b) {   // RNE
    uint ua = __builtin_bit_cast(uint, a);
    uint ub = __builtin_bit_cast(uint, b);
    uint ra = (ua + 0x7fffu + ((ua >> 16) & 1u)) >> 16;
    uint rb = (ub + 0x7fffu + ((ub >> 16) & 1u)) >> 16;
    return ra | (rb << 16);
}

// ---------- cvt emb/W -> bf16 + bucket histogram (aux pre-zeroed by memset) ----------
__global__ __launch_bounds__(256) void cvthist_kernel(const float* __restrict__ emb, ushort* __restrict__ E,
                                                      const float* __restrict__ W, ushort* __restrict__ WB,
                                                      const int* __restrict__ dst, int* __restrict__ bhist) {
    __shared__ int h[256];
    const int t = threadIdx.x;
    h[t] = 0;
    __syncthreads();
    const int gsz = gridDim.x * 256;
    for (int i = blockIdx.x * 256 + t; i < N_NODES * DIM / 4; i += gsz) {
        const float4 v = ((const float4*)emb)[i];
        uint2 p;
        p.x = pack_bf16(v.x, v.y);
        p.y = pack_bf16(v.z, v.w);
        ((uint2*)E)[i] = p;
    }
    {
        const int i = blockIdx.x * 256 + t;
        if (i < 3 * DIM * DIM / 4) {
            const float4 v = ((const float4*)W)[i];
            uint2 p;
            p.x = pack_bf16(v.x, v.y);
            p.y = pack_bf16(v.z, v.w);
            ((uint2*)WB)[i] = p;
        }
    }
    for (int e = blockIdx.x * 256 + t; e < N_EDGES; e += gsz)
        atomicAdd(&h[dst[e] >> 8], 1);
    __syncthreads();
    if (t < NBUCK && h[t]) atomicAdd(&bhist[t], h[t]);
}

// ---------- partition: local scan of bhist + block-aggregated reservation ----------
__global__ __launch_bounds__(256) void part_kernel(const int* __restrict__ src, const int* __restrict__ dst,
                                                   const int* __restrict__ bhist, int* __restrict__ bcur,
                                                   int2* __restrict__ pak) {
    __shared__ int sc[256];
    __shared__ int h[256];
    __shared__ int base[256];
    __shared__ int cur[256];
    const int t = threadIdx.x;
    const int v = (t < NBUCK) ? bhist[t] : 0;
    sc[t] = v;
    h[t] = 0; cur[t] = 0;
    __syncthreads();
    for (int o = 1; o < 256; o <<= 1) {
        int x = (t >= o) ? sc[t - o] : 0;
        __syncthreads();
        sc[t] += x;
        __syncthreads();
    }
    const int excl = sc[t] - v;
    const int e0 = blockIdx.x * PCHUNK;
    const int e1 = min(e0 + PCHUNK, N_EDGES);
    for (int i = e0 + t; i < e1; i += 256)
        atomicAdd(&h[dst[i] >> 8], 1);
    __syncthreads();
    if (t < NBUCK && h[t]) base[t] = excl + atomicAdd(&bcur[t], h[t]);
    __syncthreads();
    for (int i = e0 + t; i < e1; i += 256) {
        const int s = src[i], d = dst[i];
        const int b = d >> 8;
        const int q = atomicAdd(&cur[b], 1);
        pak[base[b] + q] = make_int2(s, d);
    }
}

// ---------- per-bucket CSR (local bhist scan) ----------
__global__ __launch_bounds__(256) void bucket_kernel(const int2* __restrict__ pak, const int* __restrict__ bhist,
                                                     int* __restrict__ off, int* __restrict__ csr) {
    __shared__ int sc[256];
    __shared__ int cnt[256];
    __shared__ int pos[256];
    const int b = blockIdx.x, t = threadIdx.x;
    const int bv = (t < NBUCK) ? bhist[t] : 0;
    sc[t] = bv;
    cnt[t] = 0;
    __syncthreads();
    for (int o = 1; o < 256; o <<= 1) {
        int x = (t >= o) ? sc[t - o] : 0;
        __syncthreads();
        sc[t] += x;
        __syncthreads();
    }
    const int e0 = (b == 0) ? 0 : sc[b - 1];     // inclusive scan -> bucket range
    const int e1 = sc[b];
    const int m = e1 - e0;
    for (int i = t; i < m; i += 256) atomicAdd(&cnt[pak[e0 + i].y & 255], 1);
    __syncthreads();
    const int c = cnt[t];
    pos[t] = c;
    __syncthreads();
    for (int o = 1; o < 256; o <<= 1) {
        int x = (t >= o) ? pos[t - o] : 0;
        __syncthreads();
        pos[t] += x;
        __syncthreads();
    }
    const int excl = pos[t] - c;
    const int node = b * 256 + t;
    if (node < N_NODES) off[node] = e0 + excl;
    if (b == 0 && t == 0) off[N_NODES] = N_EDGES;
    __syncthreads();
    pos[t] = excl;                               // reuse as scatter cursor
    __syncthreads();
    for (int i = t; i < m; i += 256) {
        const int2 p = pak[e0 + i];
        const int q = atomicAdd(&pos[p.y & 255], 1);
        csr[e0 + q] = p.x;                       // within bucket's 16KB window
    }
}

// ---------- balanced fused layer (full layers, identity node order) ----------
// 512 threads, 32 contiguous nodes. Phase 1: the block's contiguous CSR span is
// split into 32 equal EDGE slices (one per 16-lane stream) -> max work = mean.
// Partial sums flushed at node boundaries into fp32 LDS accum via atomicAdd
// (~2-3 flushes/stream). Then pack(+self,*iv) -> bf16 xs, MFMA, LN, ELU.
__global__ __launch_bounds__(512) void layerbal_kernel(
    const ushort* __restrict__ fin, ushort* __restrict__ fout,
    const int* __restrict__ off, const int* __restrict__ csr,
    const ushort* __restrict__ wb, const float* __restrict__ bias,
    const float* __restrict__ gamma, const float* __restrict__ beta, int nrows)
{
    __shared__ ushort xs[32 * XST];
    __shared__ float  ys[32 * RST];
    __shared__ int    noff[33];
    const int t = threadIdx.x;
    const int rows = blockIdx.x * 32;
    const int nvalid = min(32, nrows - rows);

    // ---- phase 0: zero accumulators, stage off[] slice ----
    for (int i = t; i < 32 * RST; i += 512) ys[i] = 0.0f;
    if (t <= nvalid) noff[t] = off[rows + t];
    __syncthreads();

    // ---- phase 1: edge-balanced gather ----
    {
        const int lx = t & 15;
        const int st = t >> 4;
        const int e0 = noff[0], e1 = noff[nvalid];
        const int per = ((e1 - e0) + 31) >> 5;
        const int s0 = e0 + st * per;
        const int s1 = min(s0 + per, e1);
        if (s0 < s1) {
            int lo = 0, hi = nvalid - 1;          // start node: noff[p] <= s0 < noff[p+1]
            while (lo < hi) {
                const int mid = (lo + hi + 1) >> 1;
                if (noff[mid] <= s0) lo = mid; else hi = mid - 1;
            }
            int p  = lo;
            int nb = noff[p + 1];
            float acc[8] = {0, 0, 0, 0, 0, 0, 0, 0};
            for (int e = s0; e < s1; e += 8) {
                const int cnt = min(8, s1 - e);
                int id[8];
                #pragma unroll
                for (int k = 0; k < 8; ++k)
                    id[k] = csr[(k < cnt) ? (e + k) : (s1 - 1)];
                uint4 v[8];
                #pragma unroll
                for (int k = 0; k < 8; ++k)
                    v[k] = ((const uint4*)(fin + (size_t)id[k] * DIM))[lx];
                #pragma unroll
                for (int k = 0; k < 8; ++k) {
                    if (k < cnt) {
                        const int ee = e + k;
                        while (ee >= nb) {        // crossed node boundary: flush
                            float* yp = ys + p * RST + lx * 8;
                            #pragma unroll
                            for (int j = 0; j < 8; ++j) atomicAdd(&yp[j], acc[j]);
                            #pragma unroll
                            for (int j = 0; j < 8; ++j) acc[j] = 0.0f;
                            ++p;
                            nb = noff[p + 1];
                        }
                        acc[0] += bf_lo(v[k].x); acc[1] += bf_hi(v[k].x);
                        acc[2] += bf_lo(v[k].y); acc[3] += bf_hi(v[k].y);
                        acc[4] += bf_lo(v[k].z); acc[5] += bf_hi(v[k].z);
                        acc[6] += bf_lo(v[k].w); acc[7] += bf_hi(v[k].w);
                    }
                }
            }
            float* yp = ys + p * RST + lx * 8;    // final flush
            #pragma unroll
            for (int j = 0; j < 8; ++j) atomicAdd(&yp[j], acc[j]);
        }
    }
    __syncthreads();

    // ---- phase 2: xs = bf16( (accum + self) * iv ) ----
    {
        const int lx = t & 15;
        const int st = t >> 4;
        uint4 p4 = make_uint4(0, 0, 0, 0);
        if (st < nvalid) {
            const uint4 q = ((const uint4*)(fin + (size_t)(rows + st) * DIM))[lx];
            const float* yr = ys + st * RST + lx * 8;
            const float iv = 1.0f / (float)(noff[st + 1] - noff[st] + 1);
            const float o0 = (yr[0] + bf_lo(q.x)) * iv, o1 = (yr[1] + bf_hi(q.x)) * iv;
            const float o2 = (yr[2] + bf_lo(q.y)) * iv, o3 = (yr[3] + bf_hi(q.y)) * iv;
            const float o4 = (yr[4] + bf_lo(q.z)) * iv, o5 = (yr[5] + bf_hi(q.z)) * iv;
            const float o6 = (yr[6] + bf_lo(q.w)) * iv, o7 = (yr[7] + bf_hi(q.w)) * iv;
            p4.x = pack_bf16(o0, o1);
            p4.y = pack_bf16(o2, o3);
            p4.z = pack_bf16(o4, o5);
            p4.w = pack_bf16(o6, o7);
        }
        *((uint4*)(xs + st * XST + lx * 8)) = p4;
    }
    __syncthreads();

    // ---- phase 3: MFMA y = x @ W^T; 8 waves, rows 2x16, cols 4x32 ----
    {
        const int wave = t >> 6, lane = t & 63;
        const int row_off = (wave >> 2) * 16;
        const int col_off = (wave & 3) * 32;
        const int lm   = lane & 15;
        const int quad = lane >> 4;
        f32x4 acc[2] = {f32x4{0,0,0,0}, f32x4{0,0,0,0}};
        const ushort* xrow = xs + (row_off + lm) * XST + quad * 8;
        const ushort* __restrict__ wrow = wb + (size_t)(col_off + lm) * DIM + quad * 8;
        #pragma unroll
        for (int kk = 0; kk < 4; ++kk) {
            const bf16x8 af = __builtin_bit_cast(bf16x8, *(const u32x4*)(xrow + kk * 32));
            #pragma unroll
            for (int c = 0; c < 2; ++c) {
                const bf16x8 bf = __builtin_bit_cast(bf16x8,
                    *(const u32x4*)(wrow + (size_t)c * 16 * DIM + kk * 32));
                acc[c] = __builtin_amdgcn_mfma_f32_16x16x32_bf16(af, bf, acc[c], 0, 0, 0);
            }
        }
        #pragma unroll
        for (int c = 0; c < 2; ++c) {
            #pragma unroll
            for (int r = 0; r < 4; ++r)
                ys[(row_off + quad * 4 + r) * RST + col_off + c * 16 + lm] = acc[c][r];
        }
    }
    __syncthreads();

    // ---- phase 4: LN + ELU; 16 threads per row, 8 dims each ----
    {
        const int r   = t >> 4;
        const int seg = t & 15;
        const int db  = seg * 8;
        const float* yr = ys + r * RST + db;
        float vs[8];
        {
            const float4 y0 = ((const float4*)yr)[0];
            const float4 y1 = ((const float4*)yr)[1];
            const float4 b0 = ((const float4*)(bias + db))[0];
            const float4 b1 = ((const float4*)(bias + db))[1];
            vs[0] = y0.x + b0.x; vs[1] = y0.y + b0.y; vs[2] = y0.z + b0.z; vs[3] = y0.w + b0.w;
            vs[4] = y1.x + b1.x; vs[5] = y1.y + b1.y; vs[6] = y1.z + b1.z; vs[7] = y1.w + b1.w;
        }
        float s1 = 0.0f, s2 = 0.0f;
        #pragma unroll
        for (int i = 0; i < 8; ++i) { s1 += vs[i]; s2 += vs[i] * vs[i]; }
        #pragma unroll
        for (int m = 1; m < 16; m <<= 1) {
            s1 += __shfl_xor(s1, m);
            s2 += __shfl_xor(s2, m);
        }
        const float mu  = s1 * (1.0f / 128.0f);
        const float var = s2 * (1.0f / 128.0f) - mu * mu;
        const float rs  = rsqrtf(var + LN_EPS);
        float ov[8];
        {
            const float4 g0 = ((const float4*)(gamma + db))[0];
            const float4 g1 = ((const float4*)(gamma + db))[1];
            const float4 t0 = ((const float4*)(beta + db))[0];
            const float4 t1 = ((const float4*)(beta + db))[1];
            float z;
            z = (vs[0] - mu) * rs * g0.x + t0.x; ov[0] = (z > 0.0f) ? z : expm1f(z);
            z = (vs[1] - mu) * rs * g0.y + t0.y; ov[1] = (z > 0.0f) ? z : expm1f(z);
            z = (vs[2] - mu) * rs * g0.z + t0.z; ov[2] = (z > 0.0f) ? z : expm1f(z);
            z = (vs[3] - mu) * rs * g0.w + t0.w; ov[3] = (z > 0.0f) ? z : expm1f(z);
            z = (vs[4] - mu) * rs * g1.x + t1.x; ov[4] = (z > 0.0f) ? z : expm1f(z);
            z = (vs[5] - mu) * rs * g1.y + t1.y; ov[5] = (z > 0.0f) ? z : expm1f(z);
            z = (vs[6] - mu) * rs * g1.z + t1.z; ov[6] = (z > 0.0f) ? z : expm1f(z);
            z = (vs[7] - mu) * rs * g1.w + t1.w; ov[7] = (z > 0.0f) ? z : expm1f(z);
        }
        const int n = rows + r;
        if (n < nrows) {
            uint4 p;
            p.x = pack_bf16(ov[0], ov[1]);
            p.y = pack_bf16(ov[2], ov[3]);
            p.z = pack_bf16(ov[4], ov[5]);
            p.w = pack_bf16(ov[6], ov[7]);
            *((uint4*)(fout + (size_t)n * DIM + db)) = p;
        }
    }
}

// ---------- per-node fused layer (uid layer 3; round-12 measured form) ----------
__global__ __launch_bounds__(512) void layeruid_kernel(
    const ushort* __restrict__ fin, float* __restrict__ fout,
    const int* __restrict__ off, const int* __restrict__ csr,
    const int* __restrict__ uidmap, const ushort* __restrict__ wb,
    const float* __restrict__ bias, const float* __restrict__ gamma,
    const float* __restrict__ beta, int nrows)
{
    __shared__ ushort xs[32 * XST];
    __shared__ float  ys[32 * RST];
    const int t = threadIdx.x;
    const int rows = blockIdx.x * 32;

    {
        const int lx   = t & 15;
        const int st   = t >> 4;
        const int slot = rows + st;
        const bool valid = slot < nrows;
        const int n  = valid ? uidmap[slot] : 0;
        const int d0 = off[n];
        int d1 = off[n + 1];
        if (!valid) d1 = d0;
        const int deg = d1 - d0;

        float a[8];
        {
            const uint4 q = ((const uint4*)(fin + (size_t)n * DIM))[lx];
            a[0]=bf_lo(q.x); a[1]=bf_hi(q.x); a[2]=bf_lo(q.y); a[3]=bf_hi(q.y);
            a[4]=bf_lo(q.z); a[5]=bf_hi(q.z); a[6]=bf_lo(q.w); a[7]=bf_hi(q.w);
        }
        const int nfull = deg >> 3;
        int e = d0;
        int id[8];
        if (nfull > 0) {
            #pragma unroll
            for (int k = 0; k < 8; ++k) id[k] = csr[e + k];
        }
        for (int r = 0; r < nfull; ++r) {
            uint4 v[8];
            #pragma unroll
            for (int k = 0; k < 8; ++k)
                v[k] = ((const uint4*)(fin + (size_t)id[k] * DIM))[lx];
            int idn[8];
            if (r + 1 < nfull) {
                #pragma unroll
                for (int k = 0; k < 8; ++k) idn[k] = csr[e + 8 + k];
            }
            #pragma unroll
            for (int k = 0; k < 8; ++k) {
                a[0] += bf_lo(v[k].x); a[1] += bf_hi(v[k].x);
                a[2] += bf_lo(v[k].y); a[3] += bf_hi(v[k].y);
                a[4] += bf_lo(v[k].z); a[5] += bf_hi(v[k].z);
                a[6] += bf_lo(v[k].w); a[7] += bf_hi(v[k].w);
            }
            if (r + 1 < nfull) {
                #pragma unroll
                for (int k = 0; k < 8; ++k) id[k] = idn[k];
            }
            e += 8;
        }
        if (e < d1) {
            const int last = d1 - 1;
            int   idt[8];
            float m[8];
            #pragma unroll
            for (int k = 0; k < 8; ++k) {
                const int ee = e + k;
                idt[k] = csr[(ee <= last) ? ee : last];
                m[k]   = (ee <= last) ? 1.0f : 0.0f;
            }
            uint4 v[8];
            #pragma unroll
            for (int k = 0; k < 8; ++k)
                v[k] = ((const uint4*)(fin + (size_t)idt[k] * DIM))[lx];
            #pragma unroll
            for (int k = 0; k < 8; ++k) {
                a[0] = fmaf(m[k], bf_lo(v[k].x), a[0]); a[1] = fmaf(m[k], bf_hi(v[k].x), a[1]);
                a[2] = fmaf(m[k], bf_lo(v[k].y), a[2]); a[3] = fmaf(m[k], bf_hi(v[k].y), a[3]);
                a[4] = fmaf(m[k], bf_lo(v[k].z), a[4]); a[5] = fmaf(m[k], bf_hi(v[k].z), a[5]);
                a[6] = fmaf(m[k], bf_lo(v[k].w), a[6]); a[7] = fmaf(m[k], bf_hi(v[k].w), a[7]);
            }
        }
        const float iv = 1.0f / (float)(deg + 1);
        uint4 p;
        p.x = pack_bf16(a[0] * iv, a[1] * iv);
        p.y = pack_bf16(a[2] * iv, a[3] * iv);
        p.z = pack_bf16(a[4] * iv, a[5] * iv);
        p.w = pack_bf16(a[6] * iv, a[7] * iv);
        *((uint4*)(xs + st * XST + lx * 8)) = p;
    }
    __syncthreads();

    {
        const int wave = t >> 6, lane = t & 63;
        const int row_off = (wave >> 2) * 16;
        const int col_off = (wave & 3) * 32;
        const int lm   = lane & 15;
        const int quad = lane >> 4;
        f32x4 acc[2] = {f32x4{0,0,0,0}, f32x4{0,0,0,0}};
        const ushort* xrow = xs + (row_off + lm) * XST + quad * 8;
        const ushort* __restrict__ wrow = wb + (size_t)(col_off + lm) * DIM + quad * 8;
        #pragma unroll
        for (int kk = 0; kk < 4; ++kk) {
            const bf16x8 af = __builtin_bit_cast(bf16x8, *(const u32x4*)(xrow + kk * 32));
            #pragma unroll
            for (int c = 0; c < 2; ++c) {
                const bf16x8 bf = __builtin_bit_cast(bf16x8,
                    *(const u32x4*)(wrow + (size_t)c * 16 * DIM + kk * 32));
                acc[c] = __builtin_amdgcn_mfma_f32_16x16x32_bf16(af, bf, acc[c], 0, 0, 0);
            }
        }
        #pragma unroll
        for (int c = 0; c < 2; ++c) {
            #pragma unroll
            for (int r = 0; r < 4; ++r)
                ys[(row_off + quad * 4 + r) * RST + col_off + c * 16 + lm] = acc[c][r];
        }
    }
    __syncthreads();

    {
        const int r   = t >> 4;
        const int seg = t & 15;
        const int db  = seg * 8;
        const float* yr = ys + r * RST + db;
        float vs[8];
        {
            const float4 y0 = ((const float4*)yr)[0];
            const float4 y1 = ((const float4*)yr)[1];
            const float4 b0 = ((const float4*)(bias + db))[0];
            const float4 b1 = ((const float4*)(bias + db))[1];
            vs[0] = y0.x + b0.x; vs[1] = y0.y + b0.y; vs[2] = y0.z + b0.z; vs[3] = y0.w + b0.w;
            vs[4] = y1.x + b1.x; vs[5] = y1.y + b1.y; vs[6] = y1.z + b1.z; vs[7] = y1.w + b1.w;
        }
        float s1 = 0.0f, s2 = 0.0f;
        #pragma unroll
        for (int i = 0; i < 8; ++i) { s1 += vs[i]; s2 += vs[i] * vs[i]; }
        #pragma unroll
        for (int m = 1; m < 16; m <<= 1) {
            s1 += __shfl_xor(s1, m);
            s2 += __shfl_xor(s2, m);
        }
        const float mu  = s1 * (1.0f / 128.0f);
        const float var = s2 * (1.0f / 128.0f) - mu * mu;
        const float rs  = rsqrtf(var + LN_EPS);
        float ov[8];
        {
            const float4 g0 = ((const float4*)(gamma + db))[0];
            const float4 g1 = ((const float4*)(gamma + db))[1];
            const float4 t0 = ((const float4*)(beta + db))[0];
            const float4 t1 = ((const float4*)(beta + db))[1];
            float z;
            z = (vs[0] - mu) * rs * g0.x + t0.x; ov[0] = (z > 0.0f) ? z : expm1f(z);
            z = (vs[1] - mu) * rs * g0.y + t0.y; ov[1] = (z > 0.0f) ? z : expm1f(z);
            z = (vs[2] - mu) * rs * g0.z + t0.z; ov[2] = (z > 0.0f) ? z : expm1f(z);
            z = (vs[3] - mu) * rs * g0.w + t0.w; ov[3] = (z > 0.0f) ? z : expm1f(z);
            z = (vs[4] - mu) * rs * g1.x + t1.x; ov[4] = (z > 0.0f) ? z : expm1f(z);
            z = (vs[5] - mu) * rs * g1.y + t1.y; ov[5] = (z > 0.0f) ? z : expm1f(z);
            z = (vs[6] - mu) * rs * g1.z + t1.z; ov[6] = (z > 0.0f) ? z : expm1f(z);
            z = (vs[7] - mu) * rs * g1.w + t1.w; ov[7] = (z > 0.0f) ? z : expm1f(z);
        }
        const int slot = rows + r;
        if (slot < nrows) {
            float* op = fout + (size_t)slot * DIM + db;
            ((float4*)op)[0] = make_float4(ov[0], ov[1], ov[2], ov[3]);
            ((float4*)op)[1] = make_float4(ov[4], ov[5], ov[6], ov[7]);
        }
    }
}

extern "C" void kernel_launch(void* const* d_in, const int* in_sizes, int n_in,
                              void* d_out, int out_size, void* d_ws, size_t ws_size,
                              hipStream_t stream) {
    const float* emb   = (const float*)d_in[0];
    const float* W     = (const float*)d_in[1];
    const float* bias  = (const float*)d_in[2];
    const float* gamma = (const float*)d_in[3];
    const float* beta  = (const float*)d_in[4];
    const int*   src   = (const int*)d_in[5];
    const int*   dst   = (const int*)d_in[6];
    const int*   uid   = (const int*)d_in[7];

    // workspace layout (~49 MB)
    ushort* E     = (ushort*)d_ws;                    // 50000*128 bf16 (embedding)
    ushort* A     = E + (size_t)N_NODES * DIM;        // 50000*128 bf16
    ushort* B     = A + (size_t)N_NODES * DIM;        // 50000*128 bf16
    ushort* WB    = B + (size_t)N_NODES * DIM;        // 3*128*128 bf16
    int*    off   = (int*)(WB + 3 * DIM * DIM);       // 50001 (+pad to 50004)
    int*    aux   = off + (N_NODES + 4);              // bhist 256 | bcur 256
    int*    bhist = aux;
    int*    bcur  = aux + 256;
    int2*   pak   = (int2*)(aux + 512);               // 800000 int2 (8B aligned)
    int*    csr   = (int*)(pak + N_EDGES);            // 800000

    hipMemsetAsync(aux, 0, 512 * sizeof(int), stream);
    cvthist_kernel<<<512, 256, 0, stream>>>(emb, E, W, WB, dst, bhist);
    part_kernel<<<(N_EDGES + PCHUNK - 1) / PCHUNK, 256, 0, stream>>>(src, dst, bhist, bcur, pak);
    bucket_kernel<<<NBUCK, 256, 0, stream>>>(pak, bhist, off, csr);

    const int lblk = (N_NODES + 31) / 32;             // 1563
    layerbal_kernel<<<lblk, 512, 0, stream>>>(E, A, off, csr, WB,
                                              bias, gamma, beta, N_NODES);
    layerbal_kernel<<<lblk, 512, 0, stream>>>(A, B, off, csr, WB + DIM * DIM,
                                              bias + DIM, gamma + DIM, beta + DIM, N_NODES);
    // layer 3: only uid nodes, compact fp32 rows straight into d_out
    layeruid_kernel<<<N_UID / 32, 512, 0, stream>>>(B, (float*)d_out, off, csr, uid,
                                                    WB + 2 * DIM * DIM, bias + 2 * DIM,
                                                    gamma + 2 * DIM, beta + 2 * DIM, N_UID);
}

// Round 15
// 230.497 us; speedup vs baseline: 1.3840x; 1.3840x over previous
//
#include <hip/hip_runtime.h>
#include <math.h>

typedef unsigned int   uint;
typedef unsigned short ushort;

#define N_NODES 50000
#define DIM     128
#define N_EDGES 800000
#define N_UID   4096
#define LN_EPS  1e-5f
#define RST     132   // padded LDS row stride for fp32 y
#define XST     136   // padded LDS row stride for bf16 x (2-way bank alias = free)
#define NBUCK   196   // ceil(50000/256) buckets of 256 nodes
#define PCHUNK  4096  // edges per part block

typedef __attribute__((ext_vector_type(8))) short bf16x8;
typedef __attribute__((ext_vector_type(4))) float f32x4;
typedef __attribute__((ext_vector_type(4))) uint  u32x4;

// ---- bf16 helpers (storage only; math fp32) ----
__device__ __forceinline__ float bf_lo(uint u) { return __builtin_bit_cast(float, u << 16); }
__device__ __forceinline__ float bf_hi(uint u) { return __builtin_bit_cast(float, u & 0xffff0000u); }
__device__ __forceinline__ uint pack_bf16(float a, float b) {   // RNE
    uint ua = __builtin_bit_cast(uint, a);
    uint ub = __builtin_bit_cast(uint, b);
    uint ra = (ua + 0x7fffu + ((ua >> 16) & 1u)) >> 16;
    uint rb = (ub + 0x7fffu + ((ub >> 16) & 1u)) >> 16;
    return ra | (rb << 16);
}

// ---------- cvt emb/W -> bf16 + bucket histogram (aux pre-zeroed by memset) ----------
__global__ __launch_bounds__(256) void cvthist_kernel(const float* __restrict__ emb, ushort* __restrict__ E,
                                                      const float* __restrict__ W, ushort* __restrict__ WB,
                                                      const int* __restrict__ dst, int* __restrict__ bhist) {
    __shared__ int h[256];
    const int t = threadIdx.x;
    h[t] = 0;
    __syncthreads();
    const int gsz = gridDim.x * 256;
    for (int i = blockIdx.x * 256 + t; i < N_NODES * DIM / 4; i += gsz) {
        const float4 v = ((const float4*)emb)[i];
        uint2 p;
        p.x = pack_bf16(v.x, v.y);
        p.y = pack_bf16(v.z, v.w);
        ((uint2*)E)[i] = p;
    }
    {
        const int i = blockIdx.x * 256 + t;
        if (i < 3 * DIM * DIM / 4) {
            const float4 v = ((const float4*)W)[i];
            uint2 p;
            p.x = pack_bf16(v.x, v.y);
            p.y = pack_bf16(v.z, v.w);
            ((uint2*)WB)[i] = p;
        }
    }
    for (int e = blockIdx.x * 256 + t; e < N_EDGES; e += gsz)
        atomicAdd(&h[dst[e] >> 8], 1);
    __syncthreads();
    if (t < NBUCK && h[t]) atomicAdd(&bhist[t], h[t]);
}

// ---------- partition: local scan of bhist + block-aggregated reservation ----------
// pak entry: src (16 bits, N_NODES<65536) | (dst&255)<<16  -> 4B instead of 8B
__global__ __launch_bounds__(256) void part_kernel(const int* __restrict__ src, const int* __restrict__ dst,
                                                   const int* __restrict__ bhist, int* __restrict__ bcur,
                                                   uint* __restrict__ pak) {
    __shared__ int sc[256];
    __shared__ int h[256];
    __shared__ int base[256];
    __shared__ int cur[256];
    const int t = threadIdx.x;
    const int v = (t < NBUCK) ? bhist[t] : 0;
    sc[t] = v;
    h[t] = 0; cur[t] = 0;
    __syncthreads();
    for (int o = 1; o < 256; o <<= 1) {
        int x = (t >= o) ? sc[t - o] : 0;
        __syncthreads();
        sc[t] += x;
        __syncthreads();
    }
    const int excl = sc[t] - v;
    const int e0 = blockIdx.x * PCHUNK;
    const int e1 = min(e0 + PCHUNK, N_EDGES);
    for (int i = e0 + t; i < e1; i += 256)
        atomicAdd(&h[dst[i] >> 8], 1);
    __syncthreads();
    if (t < NBUCK && h[t]) base[t] = excl + atomicAdd(&bcur[t], h[t]);
    __syncthreads();
    for (int i = e0 + t; i < e1; i += 256) {
        const int s = src[i], d = dst[i];
        const int b = d >> 8;
        const int q = atomicAdd(&cur[b], 1);
        pak[base[b] + q] = (uint)s | ((uint)(d & 255) << 16);
    }
}

// ---------- per-bucket CSR (local bhist scan) ----------
__global__ __launch_bounds__(256) void bucket_kernel(const uint* __restrict__ pak, const int* __restrict__ bhist,
                                                     int* __restrict__ off, int* __restrict__ csr) {
    __shared__ int sc[256];
    __shared__ int cnt[256];
    __shared__ int pos[256];
    const int b = blockIdx.x, t = threadIdx.x;
    const int bv = (t < NBUCK) ? bhist[t] : 0;
    sc[t] = bv;
    cnt[t] = 0;
    __syncthreads();
    for (int o = 1; o < 256; o <<= 1) {
        int x = (t >= o) ? sc[t - o] : 0;
        __syncthreads();
        sc[t] += x;
        __syncthreads();
    }
    const int e0 = (b == 0) ? 0 : sc[b - 1];     // inclusive scan -> bucket range
    const int e1 = sc[b];
    const int m = e1 - e0;
    for (int i = t; i < m; i += 256) atomicAdd(&cnt[(pak[e0 + i] >> 16) & 255], 1);
    __syncthreads();
    const int c = cnt[t];
    pos[t] = c;
    __syncthreads();
    for (int o = 1; o < 256; o <<= 1) {
        int x = (t >= o) ? pos[t - o] : 0;
        __syncthreads();
        pos[t] += x;
        __syncthreads();
    }
    const int excl = pos[t] - c;
    const int node = b * 256 + t;
    if (node < N_NODES) off[node] = e0 + excl;
    if (b == 0 && t == 0) off[N_NODES] = N_EDGES;
    __syncthreads();
    pos[t] = excl;                               // reuse as scatter cursor
    __syncthreads();
    for (int i = t; i < m; i += 256) {
        const uint p = pak[e0 + i];
        const int q = atomicAdd(&pos[(p >> 16) & 255], 1);
        csr[e0 + q] = (int)(p & 0xFFFFu);        // within bucket's 16KB window
    }
}

// ---------- fused layer (round-12 measured-best form) ----------
// 512 threads, 32 nodes/block. Phase 1: one 16-lane stream per node, 8 rows in
// flight, straight-line unrolled rounds (NO control flow inside a round — R9/R14
// proved any branchy bookkeeping in the round kills MLP). One barrier, then
// MFMA (C/D: col=lane&15, row=(lane>>4)*4+reg [m89]) + LN + ELU.
// nodemap!=nullptr: slot j gathers node nodemap[j]; output row is always slot j.
template <bool OUT_BF16>
__global__ __launch_bounds__(512) void layer_kernel(
    const ushort* __restrict__ fin, void* __restrict__ fout,
    const int* __restrict__ off, const int* __restrict__ csr,
    const int* __restrict__ nodemap, const ushort* __restrict__ wb,
    const float* __restrict__ bias, const float* __restrict__ gamma,
    const float* __restrict__ beta, int nrows)
{
    __shared__ ushort xs[32 * XST];
    __shared__ float  ys[32 * RST];
    const int t = threadIdx.x;
    const int rows = blockIdx.x * 32;

    // ---- phase 1: aggregate (barrier-free, 8 rows in flight) ----
    {
        const int lx   = t & 15;
        const int st   = t >> 4;
        const int slot = rows + st;
        const bool valid = slot < nrows;
        const int n  = valid ? (nodemap ? nodemap[slot] : slot) : 0;
        const int d0 = off[n];
        int d1 = off[n + 1];
        if (!valid) d1 = d0;
        const int deg = d1 - d0;

        float a[8];
        {
            const uint4 q = ((const uint4*)(fin + (size_t)n * DIM))[lx];
            a[0]=bf_lo(q.x); a[1]=bf_hi(q.x); a[2]=bf_lo(q.y); a[3]=bf_hi(q.y);
            a[4]=bf_lo(q.z); a[5]=bf_hi(q.z); a[6]=bf_lo(q.w); a[7]=bf_hi(q.w);
        }

        const int nfull = deg >> 3;
        int e = d0;
        int id[8];
        if (nfull > 0) {
            #pragma unroll
            for (int k = 0; k < 8; ++k) id[k] = csr[e + k];
        }
        for (int r = 0; r < nfull; ++r) {
            uint4 v[8];
            #pragma unroll
            for (int k = 0; k < 8; ++k)
                v[k] = ((const uint4*)(fin + (size_t)id[k] * DIM))[lx];
            int idn[8];
            if (r + 1 < nfull) {                 // prefetch next round's indices
                #pragma unroll
                for (int k = 0; k < 8; ++k) idn[k] = csr[e + 8 + k];
            }
            #pragma unroll
            for (int k = 0; k < 8; ++k) {
                a[0] += bf_lo(v[k].x); a[1] += bf_hi(v[k].x);
                a[2] += bf_lo(v[k].y); a[3] += bf_hi(v[k].y);
                a[4] += bf_lo(v[k].z); a[5] += bf_hi(v[k].z);
                a[6] += bf_lo(v[k].w); a[7] += bf_hi(v[k].w);
            }
            if (r + 1 < nfull) {
                #pragma unroll
                for (int k = 0; k < 8; ++k) id[k] = idn[k];
            }
            e += 8;
        }
        if (e < d1) {                            // one masked 8-wide tail round
            const int last = d1 - 1;
            int   idt[8];
            float m[8];
            #pragma unroll
            for (int k = 0; k < 8; ++k) {
                const int ee = e + k;
                idt[k] = csr[(ee <= last) ? ee : last];
                m[k]   = (ee <= last) ? 1.0f : 0.0f;
            }
            uint4 v[8];
            #pragma unroll
            for (int k = 0; k < 8; ++k)
                v[k] = ((const uint4*)(fin + (size_t)idt[k] * DIM))[lx];
            #pragma unroll
            for (int k = 0; k < 8; ++k) {
                a[0] = fmaf(m[k], bf_lo(v[k].x), a[0]); a[1] = fmaf(m[k], bf_hi(v[k].x), a[1]);
                a[2] = fmaf(m[k], bf_lo(v[k].y), a[2]); a[3] = fmaf(m[k], bf_hi(v[k].y), a[3]);
                a[4] = fmaf(m[k], bf_lo(v[k].z), a[4]); a[5] = fmaf(m[k], bf_hi(v[k].z), a[5]);
                a[6] = fmaf(m[k], bf_lo(v[k].w), a[6]); a[7] = fmaf(m[k], bf_hi(v[k].w), a[7]);
            }
        }

        const float iv = 1.0f / (float)(deg + 1);
        uint4 p;
        p.x = pack_bf16(a[0] * iv, a[1] * iv);
        p.y = pack_bf16(a[2] * iv, a[3] * iv);
        p.z = pack_bf16(a[4] * iv, a[5] * iv);
        p.w = pack_bf16(a[6] * iv, a[7] * iv);
        *((uint4*)(xs + st * XST + lx * 8)) = p;
    }
    __syncthreads();

    // ---- phase 2: MFMA y = x @ W^T; 8 waves, rows 2x16, cols 4x32 ----
    {
        const int wave = t >> 6, lane = t & 63;
        const int row_off = (wave >> 2) * 16;
        const int col_off = (wave & 3) * 32;
        const int lm   = lane & 15;
        const int quad = lane >> 4;
        f32x4 acc[2] = {f32x4{0,0,0,0}, f32x4{0,0,0,0}};
        const ushort* xrow = xs + (row_off + lm) * XST + quad * 8;
        const ushort* __restrict__ wrow = wb + (size_t)(col_off + lm) * DIM + quad * 8;
        #pragma unroll
        for (int kk = 0; kk < 4; ++kk) {
            const bf16x8 af = __builtin_bit_cast(bf16x8, *(const u32x4*)(xrow + kk * 32));
            #pragma unroll
            for (int c = 0; c < 2; ++c) {
                const bf16x8 bf = __builtin_bit_cast(bf16x8,
                    *(const u32x4*)(wrow + (size_t)c * 16 * DIM + kk * 32));
                acc[c] = __builtin_amdgcn_mfma_f32_16x16x32_bf16(af, bf, acc[c], 0, 0, 0);
            }
        }
        #pragma unroll
        for (int c = 0; c < 2; ++c) {
            #pragma unroll
            for (int r = 0; r < 4; ++r)
                ys[(row_off + quad * 4 + r) * RST + col_off + c * 16 + lm] = acc[c][r];
        }
    }
    __syncthreads();

    // ---- phase 3: LN + ELU; 16 threads per row, 8 dims each ----
    {
        const int r   = t >> 4;
        const int seg = t & 15;
        const int db  = seg * 8;
        const float* yr = ys + r * RST + db;
        float vs[8];
        {
            const float4 y0 = ((const float4*)yr)[0];
            const float4 y1 = ((const float4*)yr)[1];
            const float4 b0 = ((const float4*)(bias + db))[0];
            const float4 b1 = ((const float4*)(bias + db))[1];
            vs[0] = y0.x + b0.x; vs[1] = y0.y + b0.y; vs[2] = y0.z + b0.z; vs[3] = y0.w + b0.w;
            vs[4] = y1.x + b1.x; vs[5] = y1.y + b1.y; vs[6] = y1.z + b1.z; vs[7] = y1.w + b1.w;
        }
        float s1 = 0.0f, s2 = 0.0f;
        #pragma unroll
        for (int i = 0; i < 8; ++i) { s1 += vs[i]; s2 += vs[i] * vs[i]; }
        #pragma unroll
        for (int m = 1; m < 16; m <<= 1) {
            s1 += __shfl_xor(s1, m);
            s2 += __shfl_xor(s2, m);
        }
        const float mu  = s1 * (1.0f / 128.0f);
        const float var = s2 * (1.0f / 128.0f) - mu * mu;
        const float rs  = rsqrtf(var + LN_EPS);
        float ov[8];
        {
            const float4 g0 = ((const float4*)(gamma + db))[0];
            const float4 g1 = ((const float4*)(gamma + db))[1];
            const float4 t0 = ((const float4*)(beta + db))[0];
            const float4 t1 = ((const float4*)(beta + db))[1];
            float z;
            z = (vs[0] - mu) * rs * g0.x + t0.x; ov[0] = (z > 0.0f) ? z : expm1f(z);
            z = (vs[1] - mu) * rs * g0.y + t0.y; ov[1] = (z > 0.0f) ? z : expm1f(z);
            z = (vs[2] - mu) * rs * g0.z + t0.z; ov[2] = (z > 0.0f) ? z : expm1f(z);
            z = (vs[3] - mu) * rs * g0.w + t0.w; ov[3] = (z > 0.0f) ? z : expm1f(z);
            z = (vs[4] - mu) * rs * g1.x + t1.x; ov[4] = (z > 0.0f) ? z : expm1f(z);
            z = (vs[5] - mu) * rs * g1.y + t1.y; ov[5] = (z > 0.0f) ? z : expm1f(z);
            z = (vs[6] - mu) * rs * g1.z + t1.z; ov[6] = (z > 0.0f) ? z : expm1f(z);
            z = (vs[7] - mu) * rs * g1.w + t1.w; ov[7] = (z > 0.0f) ? z : expm1f(z);
        }
        const int n = rows + r;
        if (n < nrows) {
            if (OUT_BF16) {
                uint4 p;
                p.x = pack_bf16(ov[0], ov[1]);
                p.y = pack_bf16(ov[2], ov[3]);
                p.z = pack_bf16(ov[4], ov[5]);
                p.w = pack_bf16(ov[6], ov[7]);
                *((uint4*)((ushort*)fout + (size_t)n * DIM + db)) = p;
            } else {
                float* op = (float*)fout + (size_t)n * DIM + db;
                ((float4*)op)[0] = make_float4(ov[0], ov[1], ov[2], ov[3]);
                ((float4*)op)[1] = make_float4(ov[4], ov[5], ov[6], ov[7]);
            }
        }
    }
}

extern "C" void kernel_launch(void* const* d_in, const int* in_sizes, int n_in,
                              void* d_out, int out_size, void* d_ws, size_t ws_size,
                              hipStream_t stream) {
    const float* emb   = (const float*)d_in[0];
    const float* W     = (const float*)d_in[1];
    const float* bias  = (const float*)d_in[2];
    const float* gamma = (const float*)d_in[3];
    const float* beta  = (const float*)d_in[4];
    const int*   src   = (const int*)d_in[5];
    const int*   dst   = (const int*)d_in[6];
    const int*   uid   = (const int*)d_in[7];

    // workspace layout (~46 MB)
    ushort* E     = (ushort*)d_ws;                    // 50000*128 bf16 (embedding)
    ushort* A     = E + (size_t)N_NODES * DIM;        // 50000*128 bf16
    ushort* B     = A + (size_t)N_NODES * DIM;        // 50000*128 bf16
    ushort* WB    = B + (size_t)N_NODES * DIM;        // 3*128*128 bf16
    int*    off   = (int*)(WB + 3 * DIM * DIM);       // 50001 (+pad to 50004)
    int*    aux   = off + (N_NODES + 4);              // bhist 256 | bcur 256
    int*    bhist = aux;
    int*    bcur  = aux + 256;
    uint*   pak   = (uint*)(aux + 512);               // 800000 uint (packed src|dstlow)
    int*    csr   = (int*)(pak + N_EDGES);            // 800000

    hipMemsetAsync(aux, 0, 512 * sizeof(int), stream);
    cvthist_kernel<<<512, 256, 0, stream>>>(emb, E, W, WB, dst, bhist);
    part_kernel<<<(N_EDGES + PCHUNK - 1) / PCHUNK, 256, 0, stream>>>(src, dst, bhist, bcur, pak);
    bucket_kernel<<<NBUCK, 256, 0, stream>>>(pak, bhist, off, csr);

    const int lblk = (N_NODES + 31) / 32;             // 1563
    layer_kernel<true><<<lblk, 512, 0, stream>>>(E, A, off, csr, nullptr, WB,
                                                 bias, gamma, beta, N_NODES);
    layer_kernel<true><<<lblk, 512, 0, stream>>>(A, B, off, csr, nullptr, WB + DIM * DIM,
                                                 bias + DIM, gamma + DIM, beta + DIM, N_NODES);
    // layer 3: only uid nodes are read — aggregate + transform just those, fp32 into d_out
    layer_kernel<false><<<N_UID / 32, 512, 0, stream>>>(B, (float*)d_out, off, csr, uid,
                                                        WB + 2 * DIM * DIM, bias + 2 * DIM,
                                                        gamma + 2 * DIM, beta + 2 * DIM, N_UID);
}